// Round 6
// baseline (610.410 us; speedup 1.0000x reference)
//
#include <hip/hip_runtime.h>
#include <hip/hip_cooperative_groups.h>

namespace cg = cooperative_groups;

// Problem constants (match reference module)
#define VNX 360
#define VNY 160
#define VNZ 48
#define VC 4
static constexpr int PLANE  = VNZ * VNY * VNX;     // 2,764,800 voxels / batch
static constexpr int NBATCH = 8;
static constexpr int NTH    = 256;                 // threads per block
static constexpr int NBLK   = 1024;                // 4 blocks/CU -> co-resident
static constexpr int NBP    = 256;                 // points-role blocks
static constexpr int NBG    = NBLK - NBP;          // gather-role blocks
static constexpr int GTOT   = NBATCH * PLANE;      // 22,118,400 voxels
static constexpr int G4     = GTOT / 4;            // 5,529,600 uint4 groups
static constexpr int TAIL4  = 345600;              // batch-7 tail for points-role
static constexpr int SPLIT4 = G4 - TAIL4;

typedef unsigned int u32x4 __attribute__((ext_vector_type(4)));
typedef float        f32x4 __attribute__((ext_vector_type(4)));

struct Ctrl {
    unsigned int done[NBATCH];   // #points-blocks finished with batch b
    int          bnd[NBATCH + 1];// batch start offsets in the sorted point list
};

// Gather 4 consecutive voxels (one uint4 winner group) -> 4 channel planes.
__device__ __forceinline__ void gather_group(
        const unsigned int* __restrict__ winner,
        const f32x4* __restrict__ feats,
        float* __restrict__ out, unsigned int n, int g)
{
    u32x4 w = __builtin_nontemporal_load((const u32x4*)winner + g);
    const f32x4 zero = {0.f, 0.f, 0.f, 0.f};
    f32x4 f0 = (w.x < n) ? feats[w.x] : zero;
    f32x4 f1 = (w.y < n) ? feats[w.y] : zero;
    f32x4 f2 = (w.z < n) ? feats[w.z] : zero;
    f32x4 f3 = (w.w < n) ? feats[w.w] : zero;

    int v = g * 4;                 // PLANE % 4 == 0: group never crosses batch
    int b = v / PLANE;
    int r = v - b * PLANE;
    float* base = out + (size_t)b * (VC * (size_t)PLANE) + r;

    f32x4 c0 = {f0.x, f1.x, f2.x, f3.x};
    f32x4 c1 = {f0.y, f1.y, f2.y, f3.y};
    f32x4 c2 = {f0.z, f1.z, f2.z, f3.z};
    f32x4 c3 = {f0.w, f1.w, f2.w, f3.w};
    __builtin_nontemporal_store(c0, (f32x4*)(base + 0 * (size_t)PLANE));
    __builtin_nontemporal_store(c1, (f32x4*)(base + 1 * (size_t)PLANE));
    __builtin_nontemporal_store(c2, (f32x4*)(base + 2 * (size_t)PLANE));
    __builtin_nontemporal_store(c3, (f32x4*)(base + 3 * (size_t)PLANE));
}

__device__ __forceinline__ void wait_batch(Ctrl* ctl, int b) {
    if (threadIdx.x == 0) {
        while (__hip_atomic_load(&ctl->done[b], __ATOMIC_RELAXED,
                                 __HIP_MEMORY_SCOPE_AGENT) < (unsigned)NBP)
            __builtin_amdgcn_s_sleep(16);
    }
    __syncthreads();
    // Make IC-side atomicMin results visible to normal loads (invalidate L2).
    __builtin_amdgcn_fence(__ATOMIC_ACQUIRE, "agent");
}

__global__ __launch_bounds__(NTH, 4)
void vox_fused(const f32x4* __restrict__ pts,
               const int*   __restrict__ bidx,
               unsigned int* __restrict__ winner,
               Ctrl*        __restrict__ ctl,
               float*       __restrict__ out,
               int n)
{
    const int blk = blockIdx.x, tid = threadIdx.x;

    // ---- Phase 0: sentinel init (all blocks) + control setup (block 0) ----
    {
        u32x4 s = {~0u, ~0u, ~0u, ~0u};
        u32x4* w4 = (u32x4*)winner;
        for (int t = blk * NTH + tid; t < G4; t += NBLK * NTH)
            w4[t] = s;
    }
    if (blk == 0) {
        if (tid < NBATCH) {
            // agent-scope store: the zero must reach the coherent point, not
            // sit dirty in this XCD's L2 (readers use IC-level atomic loads).
            __hip_atomic_store(&ctl->done[tid], 0u, __ATOMIC_RELAXED,
                               __HIP_MEMORY_SCOPE_AGENT);
        } else if (tid >= 32 && tid < 32 + NBATCH + 1) {
            int b = tid - 32;                    // 0..8
            int lo = 0, hi = n;                  // first i with bidx[i] >= b
            if (b == 0)            { lo = 0; }
            else if (b == NBATCH)  { lo = n; }
            else {
                while (lo < hi) { int m = (lo + hi) >> 1;
                                  if (bidx[m] < b) lo = m + 1; else hi = m; }
            }
            ctl->bnd[b] = lo;
        }
    }
    cg::this_grid().sync();

    const unsigned int un = (unsigned int)n;

    if (blk < NBP) {
        // ------------------- points role -------------------
        for (int b = 0; b < NBATCH; ++b) {
            int lo = ctl->bnd[b], hi = ctl->bnd[b + 1];
            for (int i = lo + blk * NTH + tid; i < hi; i += NBP * NTH) {
                f32x4 p = pts[i];
                // (p - lo) * 5.0f — matches XLA-CPU fast-math reciprocal
                // rewrite of /0.2f; verified bit-exact (round 4).
                int xi = (int)floorf((p.x -  0.0f) * 5.0f);
                int yi = (int)floorf((p.y + 16.0f) * 5.0f);
                int zi = (int)floorf((p.z +  2.0f) * 5.0f);
                if ((unsigned)xi < VNX && (unsigned)yi < VNY && (unsigned)zi < VNZ) {
                    int flat = ((b * VNZ + zi) * VNY + yi) * VNX + xi;
                    atomicMin(&winner[flat], (unsigned int)i);
                }
            }
            __syncthreads();   // drains each thread's vmcnt -> atomics complete
            if (tid == 0)
                __hip_atomic_fetch_add(&ctl->done[b], 1u, __ATOMIC_RELEASE,
                                       __HIP_MEMORY_SCOPE_AGENT);
        }
        // ---- then help: gather the tail of batch 7 ----
        wait_batch(ctl, NBATCH - 1);
        for (int g = SPLIT4 + blk * NTH + tid; g < G4; g += NBP * NTH)
            gather_group(winner, pts, out, un, g);
    } else {
        // ------------------- gather role -------------------
        const int gj = blk - NBP;
        int cur_ready = -1;
        for (long g0 = (long)gj * NTH; g0 < SPLIT4; g0 += (long)NBG * NTH) {
            long gm = g0 + NTH - 1; if (gm > SPLIT4 - 1) gm = SPLIT4 - 1;
            int bneed = (int)((gm * 4) / PLANE);
            if (bneed > cur_ready) {            // enter a new batch: sync once
                wait_batch(ctl, bneed);
                cur_ready = bneed;
            }
            int g = (int)g0 + tid;
            if (g < SPLIT4)
                gather_group(winner, pts, out, un, g);
        }
    }
}

// ---------------------------------------------------------------------------
extern "C" void kernel_launch(void* const* d_in, const int* in_sizes, int n_in,
                              void* d_out, int out_size, void* d_ws, size_t ws_size,
                              hipStream_t stream) {
    const f32x4* pts  = (const f32x4*)d_in[0];   // [N,4] f32
    const int*   bidx = (const int*)d_in[1];     // [N] int32 on device (sorted)
    int n = in_sizes[1];

    unsigned int* winner = (unsigned int*)d_ws;              // 88,473,600 B
    Ctrl* ctl = (Ctrl*)((char*)d_ws + (size_t)GTOT * 4);     // just past winner
    float* out = (float*)d_out;

    void* args[] = { (void*)&pts, (void*)&bidx, (void*)&winner,
                     (void*)&ctl, (void*)&out, (void*)&n };
    hipLaunchCooperativeKernel((const void*)vox_fused,
                               dim3(NBLK), dim3(NTH), args, 0, stream);
}

// Round 7
// 179.205 us; speedup vs baseline: 3.4062x; 3.4062x over previous
//
#include <hip/hip_runtime.h>

// Problem constants (match reference module)
#define VNX 360
#define VNY 160
#define VNZ 48
#define VC 4
static constexpr int PLANE = VNZ * VNY * VNX;   // 2,764,800 voxels per batch

typedef unsigned int u32x4 __attribute__((ext_vector_type(4)));
typedef float        f32x4 __attribute__((ext_vector_type(4)));

// ---------------------------------------------------------------------------
// Pass 1: winner[G] = 0xFFFFFFFF sentinel (in d_ws).
// NON-TEMPORAL stores: leave no dirty copies in per-XCD L2s, so pass-2's
// IC-side atomics and pass-3's reads hit clean lines (no cross-XCD
// coherence probes). Data lands in IC (memory-side cache).
// ---------------------------------------------------------------------------
__global__ void vox_init_kernel(u32x4* __restrict__ w4, int n4) {
    int stride = gridDim.x * blockDim.x;
    u32x4 s = { ~0u, ~0u, ~0u, ~0u };
    for (int t = blockIdx.x * blockDim.x + threadIdx.x; t < n4; t += stride)
        __builtin_nontemporal_store(s, &w4[t]);
}

// ---------------------------------------------------------------------------
// Pass 2: per-point voxelization, first-point-wins via atomicMin(pid).
// Binning: (p - lo) * 5.0f (NOT /0.2f) — matches XLA-CPU fast-math
// reciprocal rewrite; verified bit-exact in round 4.
// ---------------------------------------------------------------------------
__global__ void vox_points_kernel(const float4* __restrict__ pts,
                                  const int* __restrict__ bidx,
                                  unsigned int* __restrict__ winner,
                                  int n) {
    int i = blockIdx.x * blockDim.x + threadIdx.x;
    if (i >= n) return;

    float4 p = pts[i];  // x, y, z, power
    int xi = (int)floorf((p.x -  0.0f) * 5.0f);
    int yi = (int)floorf((p.y + 16.0f) * 5.0f);
    int zi = (int)floorf((p.z +  2.0f) * 5.0f);

    if ((unsigned)xi >= VNX || (unsigned)yi >= VNY || (unsigned)zi >= VNZ)
        return;

    int b = bidx[i];
    int flat = ((b * VNZ + zi) * VNY + yi) * VNX + xi;
    atomicMin(&winner[flat], (unsigned int)i);
}

// ---------------------------------------------------------------------------
// Pass 3: gather + transpose to [B, C, Z, Y, X].
// Direct full-grid mapping (one uint4 group per thread, 21600 blocks) for
// maximal wave count -> hides the random feats-gather latency.
// Winner: NT load (read-once). Output: NT stores (write-once stream).
// ---------------------------------------------------------------------------
__global__ void vox_gather_kernel(const u32x4* __restrict__ winner4,
                                  const f32x4* __restrict__ feats,
                                  float* __restrict__ out,
                                  unsigned int n, int nvox4) {
    int t = blockIdx.x * blockDim.x + threadIdx.x;
    if (t >= nvox4) return;

    u32x4 w = __builtin_nontemporal_load(&winner4[t]);

    const f32x4 zero = { 0.f, 0.f, 0.f, 0.f };
    f32x4 f0 = (w.x < n) ? feats[w.x] : zero;
    f32x4 f1 = (w.y < n) ? feats[w.y] : zero;
    f32x4 f2 = (w.z < n) ? feats[w.z] : zero;
    f32x4 f3 = (w.w < n) ? feats[w.w] : zero;

    int v = t * 4;                   // 4 consecutive voxels, same batch
    int b = v / PLANE;               // PLANE % 4 == 0
    int r = v - b * PLANE;
    float* base = out + (size_t)b * (VC * (size_t)PLANE) + r;

    f32x4 c0 = { f0.x, f1.x, f2.x, f3.x };
    f32x4 c1 = { f0.y, f1.y, f2.y, f3.y };
    f32x4 c2 = { f0.z, f1.z, f2.z, f3.z };
    f32x4 c3 = { f0.w, f1.w, f2.w, f3.w };
    __builtin_nontemporal_store(c0, (f32x4*)(base + 0 * (size_t)PLANE));
    __builtin_nontemporal_store(c1, (f32x4*)(base + 1 * (size_t)PLANE));
    __builtin_nontemporal_store(c2, (f32x4*)(base + 2 * (size_t)PLANE));
    __builtin_nontemporal_store(c3, (f32x4*)(base + 3 * (size_t)PLANE));
}

// ---------------------------------------------------------------------------
extern "C" void kernel_launch(void* const* d_in, const int* in_sizes, int n_in,
                              void* d_out, int out_size, void* d_ws, size_t ws_size,
                              hipStream_t stream) {
    const float* rdr  = (const float*)d_in[0];   // [N,4] f32
    const int*   bidx = (const int*)d_in[1];     // [N] int32 on device
    int n = in_sizes[1];

    int G  = out_size / VC;                      // 22,118,400 voxels
    int n4 = G / 4;                              // winner uint4 count

    unsigned int* winner = (unsigned int*)d_ws;  // 88.5 MB (ws is ~1.4 GB)

    int block = 256;

    // Pass 1: sentinel init (NT stores), grid-stride
    vox_init_kernel<<<2048, block, 0, stream>>>((u32x4*)winner, n4);

    // Pass 2: scatter min point-id per voxel
    vox_points_kernel<<<(n + block - 1) / block, block, 0, stream>>>(
        (const float4*)rdr, bidx, winner, n);

    // Pass 3: gather + channel transpose, direct full grid
    vox_gather_kernel<<<(n4 + block - 1) / block, block, 0, stream>>>(
        (const u32x4*)winner, (const f32x4*)rdr, (float*)d_out,
        (unsigned int)n, n4);
}